// Round 5
// baseline (18.528 us; speedup 1.0000x reference)
//
#include <hip/hip_runtime.h>

#define N_PATCH (32 * 112 * 112)
#define N_TH    (N_PATCH / 2)   // 2 patches per thread

// Gate LDS layout (float4 units):
//  g4[2w]   (w=0..3, layer1 wire w): (a_r, a_i, b_r, b_i)         Rot = [[a,-conj(b)],[b,conj(a)]]
//  g4[2w+1]                        : (b_r-b_i, b_r+b_i, a_r-a_i, a_r+a_i)
//  g4[8+w]  (w=0..3, layer2 wire w): (a_r, a_i, b_r, b_i)
__global__ __launch_bounds__(256) void qfeat_kernel(const float* __restrict__ x,
                                                    const float* __restrict__ wts,
                                                    float* __restrict__ out) {
    __shared__ __align__(16) float4 g4[12];
    if (threadIdx.x < 8) {
        const int gid = threadIdx.x;
        float phi   = wts[gid * 3 + 0];
        float theta = wts[gid * 3 + 1];
        float omega = wts[gid * 3 + 2];
        float st, ct; sincosf(0.5f * theta, &st, &ct);
        float sp, cp; sincosf(-0.5f * (phi + omega), &sp, &cp);   // e^{-i(phi+omega)/2}
        float sm, cm; sincosf(-0.5f * (phi - omega), &sm, &cm);   // e^{-i(phi-omega)/2}
        float a_r = cp * ct, a_i = sp * ct;    // m00 = a, m11 = conj(a)
        float b_r = cm * st, b_i = sm * st;    // m10 = b, m01 = -conj(b)
        if (gid < 4) {
            g4[2 * gid]     = make_float4(a_r, a_i, b_r, b_i);
            g4[2 * gid + 1] = make_float4(b_r - b_i, b_r + b_i, a_r - a_i, a_r + a_i);
        } else {
            g4[4 + gid]     = make_float4(a_r, a_i, b_r, b_i);   // indices 8..11
        }
    }
    __syncthreads();

    // Load all gate constants once; reused by both patch sims.
    float4 gm[12];
#pragma unroll
    for (int k = 0; k < 12; ++k) gm[k] = g4[k];

    const int pid2 = blockIdx.x * 256 + threadIdx.x;   // grid exact: 784*256 == N_TH
    int jj = pid2 % 56;          // pair-of-patches column
    int t  = pid2 / 56;
    int i  = t % 112;
    int b  = t / 112;

    // Two horizontally adjacent patches share image rows 2i, 2i+1; columns 4jj..4jj+3.
    const float4 top = *reinterpret_cast<const float4*>(x + (((size_t)b * 224 + 2 * i) * 224 + 4 * jj));
    const float4 bot = *reinterpret_cast<const float4*>(x + (((size_t)b * 224 + 2 * i + 1) * 224 + 4 * jj));

    float4 res[2];
#pragma unroll
    for (int pp = 0; pp < 2; ++pp) {
        float p[4];
        if (pp == 0) { p[0] = top.x; p[1] = top.y; p[2] = bot.x; p[3] = bot.y; }
        else         { p[0] = top.z; p[1] = top.w; p[2] = bot.z; p[3] = bot.w; }

        // Encoding per wire: v0 = c^2 + i s^2, v1 = (sc, -sc); c=cos(pi p/2), s=sin(pi p/2).
        // Double angle C=cos(pi p), S=sin(pi p); hw sin/cos in revolutions: 0.5*p, p in [0,1].
        // Layer-1 Rot folded in: 12 FMA/wire using precomputed sums/diffs (v1i = -v1r).
        float ur[4][2], ui[4][2];
#pragma unroll
        for (int w = 0; w < 4; ++w) {
            float S = __builtin_amdgcn_sinf(p[w] * 0.5f);
            float C = __builtin_amdgcn_cosf(p[w] * 0.5f);
            float v0r = 0.5f + 0.5f * C;
            float v0i = 0.5f - 0.5f * C;
            float v1r = 0.5f * S;
            float4 q0 = gm[2 * w], q1 = gm[2 * w + 1];
            ur[w][0] = q0.x * v0r - q0.y * v0i - q1.x * v1r;
            ui[w][0] = q0.x * v0i + q0.y * v0r + q1.y * v1r;
            ur[w][1] = q0.z * v0r - q0.w * v0i + q1.z * v1r;
            ui[w][1] = q0.z * v0i + q0.w * v0r - q1.w * v1r;
        }

        // Tensor product (wire0 = MSB of the 4-bit state index).
        float t2r[4], t2i[4];
#pragma unroll
        for (int idx = 0; idx < 4; ++idx) {
            int b0 = idx >> 1, b1 = idx & 1;
            t2r[idx] = ur[0][b0] * ur[1][b1] - ui[0][b0] * ui[1][b1];
            t2i[idx] = ur[0][b0] * ui[1][b1] + ui[0][b0] * ur[1][b1];
        }
        float t3r[8], t3i[8];
#pragma unroll
        for (int idx = 0; idx < 8; ++idx) {
            int hi = idx >> 1, b2 = idx & 1;
            t3r[idx] = t2r[hi] * ur[2][b2] - t2i[hi] * ui[2][b2];
            t3i[idx] = t2r[hi] * ui[2][b2] + t2i[hi] * ur[2][b2];
        }
        float ar[16], ai[16];
#pragma unroll
        for (int idx = 0; idx < 16; ++idx) {
            int hi = idx >> 1, b3 = idx & 1;
            ar[idx] = t3r[hi] * ur[3][b3] - t3i[hi] * ui[3][b3];
            ai[idx] = t3r[hi] * ui[3][b3] + t3i[hi] * ur[3][b3];
        }

        // CNOT ring r=1 (register renames, free after unroll).
#pragma unroll
        for (int w = 0; w < 4; ++w) {
            const int mc = 8 >> w;
            const int mt = 8 >> ((w + 1) & 3);
#pragma unroll
            for (int idx = 0; idx < 16; ++idx) {
                if ((idx & mc) && !(idx & mt)) {
                    const int k = idx | mt;
                    float tr = ar[idx]; ar[idx] = ar[k]; ar[k] = tr;
                    float ti = ai[idx]; ai[idx] = ai[k]; ai[k] = ti;
                }
            }
        }

        // Layer-2 Rot per wire, SU(2) 4-constant form.
#pragma unroll
        for (int w = 0; w < 4; ++w) {
            float4 m = gm[8 + w];   // (a_r, a_i, b_r, b_i)
            const int mask = 8 >> w;
#pragma unroll
            for (int idx = 0; idx < 16; ++idx) {
                if (idx & mask) continue;
                const int k = idx | mask;
                float a0r = ar[idx], a0i = ai[idx];
                float a1r = ar[k],   a1i = ai[k];
                ar[idx] = m.x * a0r - m.y * a0i - m.z * a1r - m.w * a1i;
                ai[idx] = m.x * a0i + m.y * a0r - m.z * a1i + m.w * a1r;
                ar[k]   = m.z * a0r - m.w * a0i + m.x * a1r + m.y * a1i;
                ai[k]   = m.z * a0i + m.w * a0r + m.x * a1i - m.y * a1r;
            }
        }

        // CNOT ring r=2.
#pragma unroll
        for (int w = 0; w < 4; ++w) {
            const int mc = 8 >> w;
            const int mt = 8 >> ((w + 2) & 3);
#pragma unroll
            for (int idx = 0; idx < 16; ++idx) {
                if ((idx & mc) && !(idx & mt)) {
                    const int k = idx | mt;
                    float tr = ar[idx]; ar[idx] = ar[k]; ar[k] = tr;
                    float ti = ai[idx]; ai[idx] = ai[k]; ai[k] = ti;
                }
            }
        }

        // |a|^2 then partial Walsh tree (only the 4 single-Z outputs needed).
        float pb[16];
#pragma unroll
        for (int idx = 0; idx < 16; ++idx)
            pb[idx] = ar[idx] * ar[idx] + ai[idx] * ai[idx];

        float sA[8], dA[8];
#pragma unroll
        for (int k = 0; k < 8; ++k) { sA[k] = pb[2*k] + pb[2*k+1]; dA[k] = pb[2*k] - pb[2*k+1]; }
        float o3 = ((dA[0] + dA[1]) + (dA[2] + dA[3])) + ((dA[4] + dA[5]) + (dA[6] + dA[7]));

        float sB[4], dB[4];
#pragma unroll
        for (int k = 0; k < 4; ++k) { sB[k] = sA[2*k] + sA[2*k+1]; dB[k] = sA[2*k] - sA[2*k+1]; }
        float o2 = (dB[0] + dB[1]) + (dB[2] + dB[3]);

        float sC0 = sB[0] + sB[1], sC1 = sB[2] + sB[3];
        float o1 = (sB[0] - sB[1]) + (sB[2] - sB[3]);
        float o0 = sC0 - sC1;

        res[pp] = make_float4(o0, o1, o2, o3);
    }

    float4* op = reinterpret_cast<float4*>(out + (size_t)pid2 * 8);
    op[0] = res[0];
    op[1] = res[1];
}

extern "C" void kernel_launch(void* const* d_in, const int* in_sizes, int n_in,
                              void* d_out, int out_size, void* d_ws, size_t ws_size,
                              hipStream_t stream) {
    const float* x   = (const float*)d_in[0];
    const float* wts = (const float*)d_in[1];
    float* out       = (float*)d_out;
    qfeat_kernel<<<N_TH / 256, 256, 0, stream>>>(x, wts, out);
}

// Round 6
// 11.898 us; speedup vs baseline: 1.5573x; 1.5573x over previous
//
#include <hip/hip_runtime.h>

#define N_PATCH (32 * 112 * 112)

// Heisenberg-picture evaluation. Observables Z_w pulled back through the circuit
// (compile-time Clifford algebra), leaving per-wire Bloch vectors + 24 signed
// coefficient products. Per patch: 4 hw-trig + ~110 VALU ops, no state vector.
//
// Derivation summary (verified vs 4 analytic limit cases):
//  Ring2† Z_w Ring2: Z0->Z2, Z1->Z3, Z2->Z0Z2, Z3->Z1Z3.
//  Rot2†  Z  Rot2 = n.sigma, n = (-sin(th)cos(phi), sin(th)sin(phi), cos(th)).
//  Ring1† pulls (C01 C12 C23 C30 conj):
//   X0'=X0X1  Y0'=X0Y1Z2Z3  Z0'=Z1Z2Z3 ; X1'=X1X2  Y1'=Z0Y1X2  Z1'=Z0Z1
//   X2'=X2X3  Y2'=Z0Z1Y2X3  Z2'=Z0Z1Z2 ; X3'=X0X1X3 Y3'=-Y0Y1Z2Y3 Z3'=Z0Z1Z2Z3
//  Product-state expectation of a Pauli product = product of Bloch components.
//  Encoded-state Bloch: e = (S*C, -S, C*C), S=sin(pi p), C=cos(pi p); m = R1 * e.
__global__ __launch_bounds__(256) void qfeat_kernel(const float* __restrict__ x,
                                                    const float* __restrict__ wts,
                                                    float* __restrict__ out) {
    __shared__ __align__(16) float4 gs[19];
    __shared__ __align__(16) float4 nv[4];

    if (threadIdx.x < 4) {
        const int w = threadIdx.x;   // layer-1 gate, wire w: full SO(3) matrix
        float phi = wts[w*3+0], th = wts[w*3+1], om = wts[w*3+2];
        float sP,cP,sT,cT,sO,cO;
        sincosf(phi,&sP,&cP); sincosf(th,&sT,&cT); sincosf(om,&sO,&cO);
        // R1 = Rz3(om) * Ry3(th) * Rz3(phi)
        float r00 = cO*cT*cP - sO*sP, r01 = -cO*cT*sP - sO*cP, r02 = cO*sT;
        float r10 = sO*cT*cP + cO*sP, r11 = -sO*cT*sP + cO*cP, r12 = sO*sT;
        float r20 = -sT*cP,           r21 =  sT*sP,            r22 = cT;
        gs[3*w+0] = make_float4(r00, r10, r20, 0.f);     // col0 (multiplies S*C)
        gs[3*w+1] = make_float4(-r01, -r11, -r21, 0.f);  // -col1 (multiplies S; e_y = -S folded)
        gs[3*w+2] = make_float4(r02, r12, r22, 0.f);     // col2 (multiplies C^2)
    } else if (threadIdx.x < 8) {
        const int v = threadIdx.x - 4;   // layer-2 gate, wire v: only z-row needed
        float phi = wts[(4+v)*3+0], th = wts[(4+v)*3+1];
        float sP,cP,sT,cT;
        sincosf(phi,&sP,&cP); sincosf(th,&sT,&cT);
        nv[v] = make_float4(-sT*cP, sT*sP, cT, 0.f);
    }
    __syncthreads();
    if (threadIdx.x == 0) {
        float4 n0 = nv[0], n1 = nv[1], n2 = nv[2], n3 = nv[3];
        gs[12] = make_float4(n2.x, n2.y, n2.z, 0.f);                               // A (out0)
        gs[13] = make_float4(n3.x, -n3.y, n3.z, 0.f);                              // B (out1)
        gs[14] = make_float4( n0.x*n2.x, -n0.x*n2.y, -n0.x*n2.z, -n0.y*n2.x);      // C0..C3
        gs[15] = make_float4( n0.y*n2.y,  n0.y*n2.z, -n0.z*n2.x,  n0.z*n2.y);      // C4..C7
        gs[16] = make_float4( n0.z*n2.z,  n1.x*n3.x, -n1.x*n3.y, -n1.x*n3.z);      // C8, D0..D2
        gs[17] = make_float4( n1.y*n3.x,  n1.y*n3.y,  n1.y*n3.z, -n1.z*n3.x);      // D3..D6
        gs[18] = make_float4( n1.z*n3.y,  n1.z*n3.z, 0.f, 0.f);                    // D7, D8
    }
    __syncthreads();

    const int pid = blockIdx.x * 256 + threadIdx.x;   // grid exact: 1568*256 == N_PATCH
    int j = pid % 112;
    int t = pid / 112;
    int i = t % 112;
    int b = t / 112;

    // patch: wire0=x[b,2i,2j], wire1=x[b,2i,2j+1], wire2=x[b,2i+1,2j], wire3=x[b,2i+1,2j+1]
    const float2 top = *reinterpret_cast<const float2*>(x + (((size_t)b * 224 + 2 * i) * 224 + 2 * j));
    const float2 bot = *reinterpret_cast<const float2*>(x + (((size_t)b * 224 + 2 * i + 1) * 224 + 2 * j));
    float p[4] = {top.x, top.y, bot.x, bot.y};

    // Per-wire Bloch vector after encoding + layer-1 Rot: m = R1 * (S*C, -S, C^2).
    // hw sin/cos take revolutions: pi*p rad = 0.5*p rev; p in [0,1] -> no reduction.
    float mx[4], my[4], mz[4];
#pragma unroll
    for (int w = 0; w < 4; ++w) {
        float S = __builtin_amdgcn_sinf(0.5f * p[w]);
        float C = __builtin_amdgcn_cosf(0.5f * p[w]);
        float e0 = S * C, e2 = C * C;   // e1 = S (col1 sign pre-folded)
        float4 c0 = gs[3*w], c1 = gs[3*w+1], c2 = gs[3*w+2];
        mx[w] = c0.x * e0 + c1.x * S + c2.x * e2;
        my[w] = c0.y * e0 + c1.y * S + c2.y * e2;
        mz[w] = c0.z * e0 + c1.z * S + c2.z * e2;
    }

    float4 A = gs[12], B = gs[13];
    float4 c14 = gs[14], c15 = gs[15], c16 = gs[16], c17 = gs[17], c18 = gs[18];

    float x01 = mx[0]*mx[1], y01 = my[0]*my[1], z01 = mz[0]*mz[1];
    float x23 = mx[2]*mx[3], y23 = my[2]*my[3], z23 = mz[2]*mz[3];
    float y2x3 = my[2]*mx[3];

    // out0 = <Z0> : n2x*X2X3 + n2y*Z0Z1Y2X3 + n2z*Z0Z1Z2
    float o0 = A.x*x23 + A.y*(z01*y2x3) + A.z*(z01*mz[2]);
    // out1 = <Z1> : n3x*X0X1X3 - n3y*Y0Y1Z2Y3 + n3z*Z0Z1Z2Z3
    float o1 = B.x*(x01*mx[3]) + B.y*(y01*(mz[2]*my[3])) + B.z*(z01*z23);
    // out2 = <Z2> : 9 terms, coeffs C0..C8 (signs folded in)
    float o2 = c14.x*(x01*x23) + c14.y*(y01*y2x3) + c14.z*(y01*mz[2]) + c14.w*(mx[0]*my[1]*y23)
             + c15.x*(my[0]*mx[1]*mx[2]*my[3]) + c15.y*(my[0]*mx[1]*mz[3]) + c15.z*(mz[1]*y23)
             + c15.w*(mz[0]*mx[2]*my[3]) + c16.x*(mz[0]*mz[3]);
    // out3 = <Z3> : 9 terms, coeffs D0..D8
    float o3 = c16.y*(mx[0]*x23) + c16.z*(my[0]*mz[1]*y23) + c16.w*(mz[0]*my[1]*my[2]*mz[3])
             + c17.x*(my[0]*mz[1]*x23) + c17.y*(mx[0]*y23) + c17.z*(mx[1]*my[2]*mz[3])
             + c17.w*(y01*mx[3]) + c18.x*(x01*mz[2]*my[3]) + c18.y*z23;

    *reinterpret_cast<float4*>(out + (size_t)pid * 4) = make_float4(o0, o1, o2, o3);
}

extern "C" void kernel_launch(void* const* d_in, const int* in_sizes, int n_in,
                              void* d_out, int out_size, void* d_ws, size_t ws_size,
                              hipStream_t stream) {
    const float* x   = (const float*)d_in[0];
    const float* wts = (const float*)d_in[1];
    float* out       = (float*)d_out;
    qfeat_kernel<<<N_PATCH / 256, 256, 0, stream>>>(x, wts, out);
}

// Round 7
// 10.559 us; speedup vs baseline: 1.7547x; 1.1268x over previous
//
#include <hip/hip_runtime.h>

#define N_PATCH (32 * 112 * 112)
#define TPB 512

// Heisenberg-picture evaluation (derivation verified round 6, absmax 3.9e-3):
//  Ring2† Z_w Ring2: Z0->Z2, Z1->Z3, Z2->Z0Z2, Z3->Z1Z3.
//  Rot2† Z Rot2 = n.sigma, n = (-sin(th)cos(phi), sin(th)sin(phi), cos(th)).
//  Ring1† pulls each Pauli product back to a <=4-wire product (compile-time).
//  Product-state expectation = product of per-wire Bloch components.
//  Encoded Bloch: e = (S*C, -S, C^2), S=sin(pi p), C=cos(pi p); m = R1*e.
// This round: o2/o3 computed as double contractions n0·(T n2), n1·(T' n3)
// per-thread (no thread-0 coefficient phase, single barrier), loads hoisted
// above the prologue, hw trig in the prologue.
__global__ __launch_bounds__(TPB) void qfeat_kernel(const float* __restrict__ x,
                                                    const float* __restrict__ wts,
                                                    float* __restrict__ out) {
    const int pid = blockIdx.x * TPB + threadIdx.x;   // grid exact: 784*512 == N_PATCH
    int j = pid % 112;
    int t = pid / 112;
    int i = t % 112;
    int b = t / 112;

    // Patch loads issued FIRST: HBM latency overlaps the prologue + barrier.
    // wire0=x[b,2i,2j], wire1=x[b,2i,2j+1], wire2=x[b,2i+1,2j], wire3=x[b,2i+1,2j+1]
    const float2 top = *reinterpret_cast<const float2*>(x + (((size_t)b * 224 + 2 * i) * 224 + 2 * j));
    const float2 bot = *reinterpret_cast<const float2*>(x + (((size_t)b * 224 + 2 * i + 1) * 224 + 2 * j));

    __shared__ __align__(16) float4 gcol[12];  // layer-1 SO(3) columns, signs pre-folded
    __shared__ __align__(16) float4 nv[4];     // layer-2 z-rows

    if (threadIdx.x < 8) {
        const float INV2PI = 0.15915494309189535f;  // hw trig takes revolutions
        if (threadIdx.x < 4) {
            const int w = threadIdx.x;
            float phi = wts[w*3+0], th = wts[w*3+1], om = wts[w*3+2];
            float sP = __builtin_amdgcn_sinf(phi*INV2PI), cP = __builtin_amdgcn_cosf(phi*INV2PI);
            float sT = __builtin_amdgcn_sinf(th *INV2PI), cT = __builtin_amdgcn_cosf(th *INV2PI);
            float sO = __builtin_amdgcn_sinf(om *INV2PI), cO = __builtin_amdgcn_cosf(om *INV2PI);
            // R1 = Rz3(om)*Ry3(th)*Rz3(phi)
            float r00 = cO*cT*cP - sO*sP, r01 = -cO*cT*sP - sO*cP, r02 = cO*sT;
            float r10 = sO*cT*cP + cO*sP, r11 = -sO*cT*sP + cO*cP, r12 = sO*sT;
            float r20 = -sT*cP,           r21 =  sT*sP,            r22 = cT;
            gcol[3*w+0] = make_float4(r00, r10, r20, 0.f);     // col0 (× S*C)
            gcol[3*w+1] = make_float4(-r01, -r11, -r21, 0.f);  // -col1 (× S; e_y=-S folded)
            gcol[3*w+2] = make_float4(r02, r12, r22, 0.f);     // col2 (× C^2)
        } else {
            const int v = threadIdx.x - 4;
            float phi = wts[(4+v)*3+0], th = wts[(4+v)*3+1];
            float sP = __builtin_amdgcn_sinf(phi*INV2PI), cP = __builtin_amdgcn_cosf(phi*INV2PI);
            float sT = __builtin_amdgcn_sinf(th *INV2PI), cT = __builtin_amdgcn_cosf(th *INV2PI);
            nv[v] = make_float4(-sT*cP, sT*sP, cT, 0.f);
        }
    }
    __syncthreads();

    float p[4] = {top.x, top.y, bot.x, bot.y};

    // Per-wire Bloch after encoding + layer-1 Rot: m = R1 * (S*C, -S, C^2).
    // pi*p rad = 0.5*p rev; p in [0,1].
    float mx[4], my[4], mz[4];
#pragma unroll
    for (int w = 0; w < 4; ++w) {
        float S = __builtin_amdgcn_sinf(0.5f * p[w]);
        float C = __builtin_amdgcn_cosf(0.5f * p[w]);
        float e0 = S * C, e2 = C * C;
        float4 c0 = gcol[3*w], c1 = gcol[3*w+1], c2 = gcol[3*w+2];
        mx[w] = c0.x * e0 + c1.x * S + c2.x * e2;
        my[w] = c0.y * e0 + c1.y * S + c2.y * e2;
        mz[w] = c0.z * e0 + c1.z * S + c2.z * e2;
    }

    float4 n0 = nv[0], n1 = nv[1], n2 = nv[2], n3 = nv[3];

    float x01 = mx[0]*mx[1], y01 = my[0]*my[1], z01 = mz[0]*mz[1];
    float x23 = mx[2]*mx[3], y23 = my[2]*my[3], z23 = mz[2]*mz[3];
    float y2x3 = my[2]*mx[3];

    // out0 = <Z0>
    float o0 = n2.x*x23 + n2.y*(z01*y2x3) + n2.z*(z01*mz[2]);
    // out1 = <Z1>
    float o1 = n3.x*(x01*mx[3]) - n3.y*(y01*(mz[2]*my[3])) + n3.z*(z01*z23);
    // out2 = <Z2> = n0 . (T n2)  (signs from round-6 verified coefficient table)
    float ix =  n2.x*(x01*x23)          - n2.y*(y01*y2x3)           - n2.z*(y01*mz[2]);
    float iy = -n2.x*(mx[0]*my[1]*y23)  + n2.y*(my[0]*mx[1]*mx[2]*my[3]) + n2.z*(my[0]*mx[1]*mz[3]);
    float iz = -n2.x*(mz[1]*y23)        + n2.y*(mz[0]*mx[2]*my[3])  + n2.z*(mz[0]*mz[3]);
    float o2 = n0.x*ix + n0.y*iy + n0.z*iz;
    // out3 = <Z3> = n1 . (T' n3)
    float jx =  n3.x*(mx[0]*x23)        - n3.y*(my[0]*mz[1]*y23)    - n3.z*(mz[0]*my[1]*my[2]*mz[3]);
    float jy =  n3.x*(my[0]*mz[1]*x23)  + n3.y*(mx[0]*y23)          + n3.z*(mx[1]*my[2]*mz[3]);
    float jz = -n3.x*(y01*mx[3])        + n3.y*(x01*mz[2]*my[3])    + n3.z*z23;
    float o3 = n1.x*jx + n1.y*jy + n1.z*jz;

    *reinterpret_cast<float4*>(out + (size_t)pid * 4) = make_float4(o0, o1, o2, o3);
}

extern "C" void kernel_launch(void* const* d_in, const int* in_sizes, int n_in,
                              void* d_out, int out_size, void* d_ws, size_t ws_size,
                              hipStream_t stream) {
    const float* x   = (const float*)d_in[0];
    const float* wts = (const float*)d_in[1];
    float* out       = (float*)d_out;
    qfeat_kernel<<<N_PATCH / TPB, TPB, 0, stream>>>(x, wts, out);
}

// Round 8
// 10.367 us; speedup vs baseline: 1.7873x; 1.0186x over previous
//
#include <hip/hip_runtime.h>

#define N_PATCH (32 * 112 * 112)
#define TPB 512

// Heisenberg-picture evaluation (derivation verified round 6, absmax 3.9e-3):
//  Ring2† Z_w Ring2: Z0->Z2, Z1->Z3, Z2->Z0Z2, Z3->Z1Z3.
//  Rot2† Z Rot2 = n.sigma, n = (-sin(th)cos(phi), sin(th)sin(phi), cos(th)).
//  Ring1† pulls each Pauli product back to a <=4-wire product (compile-time).
//  Product-state expectation = product of per-wire Bloch components.
//  Encoded Bloch: e = (S*C, -S, C^2), S=sin(pi p), C=cos(pi p); m = R1*e.
//
// This round: NO LDS, NO barrier. Every lane computes gate (lane&7)'s
// constants (hw trig, parallel), then v_readlane broadcasts all 48 constants
// into SGPRs — FMA operands come straight from the scalar file.

__device__ __forceinline__ float rl(float v, int lane) {
    return __int_as_float(__builtin_amdgcn_readlane(__float_as_int(v), lane));
}

__global__ __launch_bounds__(TPB) void qfeat_kernel(const float* __restrict__ x,
                                                    const float* __restrict__ wts,
                                                    float* __restrict__ out) {
    const int pid = blockIdx.x * TPB + threadIdx.x;   // grid exact: 784*512 == N_PATCH
    int j = pid % 112;
    int t = pid / 112;
    int i = t % 112;
    int b = t / 112;

    // Patch loads first: HBM latency hides under the constant computation.
    // wire0=x[b,2i,2j], wire1=x[b,2i,2j+1], wire2=x[b,2i+1,2j], wire3=x[b,2i+1,2j+1]
    const float2 top = *reinterpret_cast<const float2*>(x + (((size_t)b * 224 + 2 * i) * 224 + 2 * j));
    const float2 bot = *reinterpret_cast<const float2*>(x + (((size_t)b * 224 + 2 * i + 1) * 224 + 2 * j));

    // ---- per-lane gate-constant computation (gate g = lane & 7) ----
    const int lane = threadIdx.x & 63;
    const int g = lane & 7;
    const float INV2PI = 0.15915494309189535f;   // hw trig takes revolutions
    float phi = wts[g * 3 + 0], th = wts[g * 3 + 1], om = wts[g * 3 + 2];
    float sP = __builtin_amdgcn_sinf(phi * INV2PI), cP = __builtin_amdgcn_cosf(phi * INV2PI);
    float sT = __builtin_amdgcn_sinf(th  * INV2PI), cT = __builtin_amdgcn_cosf(th  * INV2PI);
    float sO = __builtin_amdgcn_sinf(om  * INV2PI), cO = __builtin_amdgcn_cosf(om  * INV2PI);
    // Layer-1 SO(3) matrix R1 = Rz3(om)*Ry3(th)*Rz3(phi)  (used from lanes 0..3)
    float r00 = cO*cT*cP - sO*sP, r01 = -cO*cT*sP - sO*cP, r02 = cO*sT;
    float r10 = sO*cT*cP + cO*sP, r11 = -sO*cT*sP + cO*cP, r12 = sO*sT;
    float r20 = -sT*cP,           r21 =  sT*sP,            r22 = cT;
    // Layer-2 z-row (used from lanes 4..7)
    float nxl = -sT * cP, nyl = sT * sP, nzl = cT;

    // ---- broadcast to SGPRs via readlane (uniform => scalar file) ----
    // Layer-1 matrices: wire w from lane w.
    float a00[4], a01[4], a02[4], a10[4], a11[4], a12[4], a20[4], a21[4], a22[4];
#pragma unroll
    for (int w = 0; w < 4; ++w) {
        a00[w] = rl(r00, w); a01[w] = rl(r01, w); a02[w] = rl(r02, w);
        a10[w] = rl(r10, w); a11[w] = rl(r11, w); a12[w] = rl(r12, w);
        a20[w] = rl(r20, w); a21[w] = rl(r21, w); a22[w] = rl(r22, w);
    }
    // Layer-2 z-rows: wire v from lane 4+v.
    float n0x = rl(nxl, 4), n0y = rl(nyl, 4), n0z = rl(nzl, 4);
    float n1x = rl(nxl, 5), n1y = rl(nyl, 5), n1z = rl(nzl, 5);
    float n2x = rl(nxl, 6), n2y = rl(nyl, 6), n2z = rl(nzl, 6);
    float n3x = rl(nxl, 7), n3y = rl(nyl, 7), n3z = rl(nzl, 7);

    // ---- per-patch Bloch vectors: m = R1 * (S*C, -S, C^2) ----
    float p[4] = {top.x, top.y, bot.x, bot.y};
    float mx[4], my[4], mz[4];
#pragma unroll
    for (int w = 0; w < 4; ++w) {
        float S = __builtin_amdgcn_sinf(0.5f * p[w]);   // pi*p rad = 0.5*p rev, p in [0,1]
        float C = __builtin_amdgcn_cosf(0.5f * p[w]);
        float e0 = S * C, e2 = C * C;
        mx[w] = a00[w] * e0 - a01[w] * S + a02[w] * e2;
        my[w] = a10[w] * e0 - a11[w] * S + a12[w] * e2;
        mz[w] = a20[w] * e0 - a21[w] * S + a22[w] * e2;
    }

    float x01 = mx[0]*mx[1], y01 = my[0]*my[1], z01 = mz[0]*mz[1];
    float x23 = mx[2]*mx[3], y23 = my[2]*my[3], z23 = mz[2]*mz[3];
    float y2x3 = my[2]*mx[3];

    // out0 = <Z0>
    float o0 = n2x*x23 + n2y*(z01*y2x3) + n2z*(z01*mz[2]);
    // out1 = <Z1>
    float o1 = n3x*(x01*mx[3]) - n3y*(y01*(mz[2]*my[3])) + n3z*(z01*z23);
    // out2 = <Z2> = n0 . (T n2)   (signs from round-6 verified coefficient table)
    float ix =  n2x*(x01*x23)          - n2y*(y01*y2x3)               - n2z*(y01*mz[2]);
    float iy = -n2x*(mx[0]*my[1]*y23)  + n2y*(my[0]*mx[1]*mx[2]*my[3]) + n2z*(my[0]*mx[1]*mz[3]);
    float iz = -n2x*(mz[1]*y23)        + n2y*(mz[0]*mx[2]*my[3])      + n2z*(mz[0]*mz[3]);
    float o2 = n0x*ix + n0y*iy + n0z*iz;
    // out3 = <Z3> = n1 . (T' n3)
    float jx =  n3x*(mx[0]*x23)        - n3y*(my[0]*mz[1]*y23)        - n3z*(mz[0]*my[1]*my[2]*mz[3]);
    float jy =  n3x*(my[0]*mz[1]*x23)  + n3y*(mx[0]*y23)              + n3z*(mx[1]*my[2]*mz[3]);
    float jz = -n3x*(y01*mx[3])        + n3y*(x01*mz[2]*my[3])        + n3z*z23;
    float o3 = n1x*jx + n1y*jy + n1z*jz;

    *reinterpret_cast<float4*>(out + (size_t)pid * 4) = make_float4(o0, o1, o2, o3);
}

extern "C" void kernel_launch(void* const* d_in, const int* in_sizes, int n_in,
                              void* d_out, int out_size, void* d_ws, size_t ws_size,
                              hipStream_t stream) {
    const float* x   = (const float*)d_in[0];
    const float* wts = (const float*)d_in[1];
    float* out       = (float*)d_out;
    qfeat_kernel<<<N_PATCH / TPB, TPB, 0, stream>>>(x, wts, out);
}